// Round 16
// baseline (104.627 us; speedup 1.0000x reference)
//
#include <hip/hip_runtime.h>
#include <math.h>

#define HH 512
#define WW 512
#define NTOT (64u*512u*512u)
#define TS 128
#define TROWS 132
#define TCH 18
#define TPIT 152        // pitched LDS (MODE0): 304 B/row
#define TPL 144         // linear LDS pitch (2-tile kernels): task*8 == row*144+ch*8
#define NTASK (TROWS*TCH)   // 2376
#define NTASKP 2432         // NTASK rounded up to whole waves
#define NITER 10

typedef __attribute__((ext_vector_type(8))) short short8;
typedef __attribute__((ext_vector_type(4))) float f32x4;

__device__ __forceinline__ float fsqrtf(float x) { return __builtin_amdgcn_sqrtf(x); }

__device__ __forceinline__ float shrinkf(float x, float l) {
    float a = x - l, b = x + l;
    return x + 0.5f * (fsqrtf(__builtin_fmaf(a, a, 1.f)) - fsqrtf(__builtin_fmaf(b, b, 1.f)));
}

__device__ __forceinline__ float bf2f(unsigned int u) {
    union { unsigned int i; float f; } cv; cv.i = u << 16; return cv.f;
}
__device__ __forceinline__ float lo2f(unsigned int p) {
    union { unsigned int i; float f; } cv; cv.i = p << 16; return cv.f;
}
__device__ __forceinline__ float hi2f(unsigned int p) {
    union { unsigned int i; float f; } cv; cv.i = p & 0xffff0000u; return cv.f;
}

__device__ __forceinline__ unsigned int cvtpk(float lo, float hi) {
    unsigned int r;
    asm("v_cvt_pk_bf16_f32 %0, %1, %2" : "=v"(r) : "v"(lo), "v"(hi));
    return r;
}

__device__ __forceinline__ void bf8(uint4 u, float* f) {
    f[0] = bf2f(u.x & 0xffffu); f[1] = bf2f(u.x >> 16);
    f[2] = bf2f(u.y & 0xffffu); f[3] = bf2f(u.y >> 16);
    f[4] = bf2f(u.z & 0xffffu); f[5] = bf2f(u.z >> 16);
    f[6] = bf2f(u.w & 0xffffu); f[7] = bf2f(u.w >> 16);
}

__device__ __forceinline__ void gload16(const unsigned short* g, unsigned short* l) {
    __builtin_amdgcn_global_load_lds(
        (const __attribute__((address_space(1))) void*)g,
        (__attribute__((address_space(3))) void*)l,
        16, 0, 0);
}

// stats over 4096 per-wave partial pairs: 16/thread (f64) -> butterfly -> ONE barrier
__device__ __forceinline__ void stats_fast(
    const float* __restrict__ part, double* __restrict__ sbuf,
    int tid, int lane, int wv,
    float gam, float bet, float& scl_out, float& shf_out)
{
    double sd = 0.0, qd = 0.0;
#pragma unroll
    for (int k = 0; k < 16; k++) {
        const int i = tid + k * 256;
        sd += (double)part[2 * i];
        qd += (double)part[2 * i + 1];
    }
#pragma unroll
    for (int off = 32; off > 0; off >>= 1) {
        sd += __shfl_xor(sd, off);
        qd += __shfl_xor(qd, off);
    }
    if (lane == 0) { sbuf[2 * wv] = sd; sbuf[2 * wv + 1] = qd; }
    __syncthreads();   // also drains vmcnt: pre-issued staging has landed
    const double S = sbuf[0] + sbuf[2] + sbuf[4] + sbuf[6];
    const double Q = sbuf[1] + sbuf[3] + sbuf[5] + sbuf[7];
    const double mean = S / (double)NTOT;
    const double var  = Q / (double)NTOT - mean * mean;
    const double scl  = (double)gam / sqrt(var + 1e-5);
    scl_out = (float)scl;
    shf_out = (float)((double)bet - mean * scl);
}

// ================= MODE0 conv (round-15 proven, unchanged) =================
template <int MODE, bool OBF>
__global__ __launch_bounds__(256, 4) void conv_k(
    const float* __restrict__ yin,
    const unsigned short* __restrict__ t1,
    const unsigned short* __restrict__ t2,
    unsigned short* __restrict__ outbf,
    float* __restrict__ outf32,
    const float* __restrict__ wgt,
    const float* __restrict__ bias,
    const float* __restrict__ lambd,
    float* __restrict__ partials)
{
    __shared__ unsigned short tile[TROWS * TPIT];

    const int tid = threadIdx.x;
    const int lin = blockIdx.x;
    const int swz = ((lin & 7) << 7) | (lin >> 3);
    const int img = swz >> 4;
    const int rem = swz & 15;
    const int by = ((rem >> 2) & 3) * TS;
    const int bx = (rem & 3) * TS;
    const size_t ibase = (size_t)img * (HH * WW);

    const int lane = tid & 63;
    const int lm = lane & 15;
    const int kb = lane >> 4;
    const int wv = tid >> 6;

    float wloc[25];
#pragma unroll
    for (int i = 0; i < 25; i++) wloc[i] = wgt[i];
    const int basei = kb * 8 - lm - 6;
    short8 bfr[5];
#pragma unroll
    for (int ky = 0; ky < 5; ky++) {
        unsigned pkw[4];
#pragma unroll
        for (int jj = 0; jj < 4; jj++) {
            float v0 = 0.f, v1 = 0.f;
            const int i0 = basei + 2 * jj, i1 = i0 + 1;
#pragma unroll
            for (int t = 0; t < 5; t++) {
                if (i0 == t) v0 = wloc[ky * 5 + t];
                if (i1 == t) v1 = wloc[ky * 5 + t];
            }
            pkw[jj] = cvtpk(v0, v1);
        }
        union { unsigned u[4]; short8 s; } cv;
        cv.u[0]=pkw[0]; cv.u[1]=pkw[1]; cv.u[2]=pkw[2]; cv.u[3]=pkw[3];
        bfr[ky] = cv.s;
    }

    auto loadT = [&](int task, uint4& A, uint4& B) {
        A = make_uint4(0u,0u,0u,0u); B = make_uint4(0u,0u,0u,0u);
        const int row = task / TCH;
        const int ch  = task - row * TCH;
        const int gy  = by + row - 2;
        const int gx0 = bx + ch * 8 - 8;
        if (task < NTASK && gy >= 0 && gy < HH && gx0 >= 0 && gx0 <= WW - 8) {
            const size_t g = ibase + (size_t)gy * WW + gx0;
            A = *(const uint4*)(yin + g);
            B = *(const uint4*)(yin + g + 4);
        }
    };

    uint4 sA0, sB0, sA1, sB1, sA2, sB2;
    loadT(tid,        sA0, sB0);
    loadT(tid + 256,  sA1, sB1);
    loadT(tid + 512,  sA2, sB2);

    auto procT = [&](int task, uint4 A, uint4 B) {
        const int row = task / TCH;
        const int ch  = task - row * TCH;
        uint4 pk = make_uint4(0u,0u,0u,0u);
        const float4 a = *(const float4*)&A;
        const float4 b = *(const float4*)&B;
        pk.x = cvtpk(a.x, a.y); pk.y = cvtpk(a.z, a.w);
        pk.z = cvtpk(b.x, b.y); pk.w = cvtpk(b.z, b.w);
        const int gy  = by + row - 2;
        const int gx0 = bx + ch * 8 - 8;
        if (!(gy >= 0 && gy < HH && gx0 >= 0 && gx0 <= WW - 8))
            pk = make_uint4(0u,0u,0u,0u);
        *(uint4*)&tile[row * TPIT + ch * 8] = pk;
    };

#pragma unroll
    for (int t = 0; t < NITER; t++) {
        const int task = tid + t * 256;
        if (task < NTASK) procT(task, sA0, sB0);
        sA0 = sA1; sB0 = sB1;
        sA1 = sA2; sB1 = sB2;
        if (t + 3 < NITER) loadT(tid + (t + 3) * 256, sA2, sB2);
        else { sA2 = make_uint4(0u,0u,0u,0u); sB2 = make_uint4(0u,0u,0u,0u); }
    }

    const float b0 = bias[0];
    __syncthreads();

    const int r0w = wv * 32;
    f32x4 acc[2][8];
#pragma unroll
    for (int st = 0; st < 2; st++)
#pragma unroll
        for (int ct = 0; ct < 8; ct++)
            acc[st][ct] = (f32x4){0.f, 0.f, 0.f, 0.f};

#pragma unroll
    for (int ky = 0; ky < 5; ky++) {
        const short8 b = bfr[ky];
#pragma unroll
        for (int st = 0; st < 2; st++) {
            const unsigned short* ab = &tile[(r0w + st * 16 + lm + ky) * TPIT + kb * 8];
#pragma unroll
            for (int ct = 0; ct < 8; ct++) {
                short8 a = *(const short8*)(ab + ct * 16);
                acc[st][ct] = __builtin_amdgcn_mfma_f32_16x16x32_bf16(a, b, acc[st][ct], 0, 0, 0);
            }
        }
    }

    float s = 0.f, q = 0.f;
#pragma unroll
    for (int st = 0; st < 2; st++) {
#pragma unroll
        for (int ct = 0; ct < 8; ct++) {
            const f32x4 a = acc[st][ct];
            const int grow0 = by + r0w + st * 16 + kb * 4;
            const size_t base = ibase + (size_t)grow0 * WW + bx + ct * 16 + lm;
            unsigned p01 = cvtpk(a[0] + b0, a[1] + b0);
            unsigned p23 = cvtpk(a[2] + b0, a[3] + b0);
            outbf[base]          = (unsigned short)(p01 & 0xffffu);
            outbf[base + WW]     = (unsigned short)(p01 >> 16);
            outbf[base + 2 * WW] = (unsigned short)(p23 & 0xffffu);
            outbf[base + 3 * WW] = (unsigned short)(p23 >> 16);
            float fr0 = lo2f(p01), fr1 = hi2f(p01), fr2 = lo2f(p23), fr3 = hi2f(p23);
            s += fr0 + fr1 + fr2 + fr3;
            q = __builtin_fmaf(fr0, fr0, __builtin_fmaf(fr1, fr1,
                __builtin_fmaf(fr2, fr2, __builtin_fmaf(fr3, fr3, q))));
        }
    }

#pragma unroll
    for (int off = 32; off > 0; off >>= 1) {
        s += __shfl_xor(s, off);
        q += __shfl_xor(q, off);
    }
    if (lane == 0) {
        partials[(swz * 4 + wv) * 2]     = s;
        partials[(swz * 4 + wv) * 2 + 1] = q;
    }
}

// ============= 2-tile pipelined conv (MODE 1 / MODE 2), 512 blocks =============
// Per block: tiles g0=2*bswz, g1=g0+1 (same image, adjacent). Double-buffered
// linear LDS (pitch TPL=144, zero bank conflicts per round-10 PMC). Tile1's
// async loads are issued BEFORE tile0's MFMA+store -> store0 overlaps read1.
template <int MODE, bool OBF>
__global__ __launch_bounds__(256, 2) void conv2t_k(
    const unsigned short* __restrict__ t1in,
    const unsigned short* __restrict__ t2in,
    unsigned short* __restrict__ outbf,
    float* __restrict__ outf32,
    const float* __restrict__ wgt,
    const float* __restrict__ bias,
    const float* __restrict__ prevPart,
    const float* __restrict__ statsIn,
    float* __restrict__ statsOut,
    const float* __restrict__ gamma,
    const float* __restrict__ beta,
    const float* __restrict__ lambd,
    float* __restrict__ partials)
{
    __shared__ unsigned short bufA[NTASKP * 8];   // 38,912 B
    __shared__ unsigned short bufB[NTASKP * 8];   // 38,912 B
    __shared__ double sbuf[8];

    const int tid = threadIdx.x;
    const int lin = blockIdx.x;                   // 0..511
    const int bswz = ((lin & 7) << 6) | (lin >> 3);   // bijective; XCD-chunked
    const int g0 = bswz * 2, g1 = g0 + 1;
    const int img = g0 >> 4;
    const int rem0 = g0 & 15, rem1 = g1 & 15;
    const int by0 = ((rem0 >> 2) & 3) * TS, bx0 = (rem0 & 3) * TS;
    const int by1 = ((rem1 >> 2) & 3) * TS, bx1 = (rem1 & 3) * TS;
    const size_t ibase = (size_t)img * (HH * WW);

    const int lane = tid & 63;
    const int lm = lane & 15;
    const int kb = lane >> 4;
    const int wv = tid >> 6;

    float wloc[25];
#pragma unroll
    for (int i = 0; i < 25; i++) wloc[i] = wgt[i];
    const int basei = kb * 8 - lm - 6;
    short8 bfr[5];
#pragma unroll
    for (int ky = 0; ky < 5; ky++) {
        unsigned pkw[4];
#pragma unroll
        for (int jj = 0; jj < 4; jj++) {
            float v0 = 0.f, v1 = 0.f;
            const int i0 = basei + 2 * jj, i1 = i0 + 1;
#pragma unroll
            for (int t = 0; t < 5; t++) {
                if (i0 == t) v0 = wloc[ky * 5 + t];
                if (i1 == t) v1 = wloc[ky * 5 + t];
            }
            pkw[jj] = cvtpk(v0, v1);
        }
        union { unsigned u[4]; short8 s; } cv;
        cv.u[0]=pkw[0]; cv.u[1]=pkw[1]; cv.u[2]=pkw[2]; cv.u[3]=pkw[3];
        bfr[ky] = cv.s;
    }
    const float b0 = bias[0];

    // async t1 staging into linear buffer (round-10-proven, incl. pad guard)
    auto issue_t1 = [&](int by, int bx, unsigned short* buf) {
#pragma unroll
        for (int r = 0; r < NITER; r++) {
            const int task0 = r * 256 + wv * 64;
            if (task0 < NTASK) {
                const int task = task0 + lane;
                const int row = task / TCH;
                const int ch  = task - row * TCH;
                const int gy  = by + row - 2;
                const int gx0 = bx + ch * 8 - 8;
                const bool ok = (task < NTASK) && gy >= 0 && gy < HH &&
                                gx0 >= 0 && gx0 <= WW - 8;
                const size_t g = ok ? (ibase + (size_t)gy * WW + gx0) : ibase;
                gload16(t1in + g, &buf[task * 8]);
            }
        }
    };

    // 10 named t2 registers per thread (rule #20: no runtime-indexed arrays)
    struct R10 { uint4 a,b,c,d,e,f,g,h,i,j; };
    auto load_t2 = [&](int by, int bx, R10& r) {
        auto L = [&](int t) -> uint4 {
            const int task = tid + t * 256;
            const int row = task / TCH;
            const int ch  = task - row * TCH;
            const int gy  = by + row - 2;
            const int gx0 = bx + ch * 8 - 8;
            uint4 A = make_uint4(0u,0u,0u,0u);
            if (task < NTASK && gy >= 0 && gy < HH && gx0 >= 0 && gx0 <= WW - 8)
                A = *(const uint4*)(t2in + ibase + (size_t)gy * WW + gx0);
            return A;
        };
        r.a=L(0); r.b=L(1); r.c=L(2); r.d=L(3); r.e=L(4);
        r.f=L(5); r.g=L(6); r.h=L(7); r.i=L(8); r.j=L(9);
    };

    float s1 = 0.f, h1 = 0.f, s2v = 0.f, h2 = 0.f, lam = 0.f;

    // in-place transform of one staged tile
    auto xform = [&](int by, int bx, unsigned short* buf, const R10& r2) {
        auto X = [&](int t, uint4 rt2) {
            const int task = tid + t * 256;
            if (task >= NTASK) return;
            const int row = task / TCH;
            const int ch  = task - row * TCH;
            const int gy  = by + row - 2;
            const int gx0 = bx + ch * 8 - 8;
            const bool ok = gy >= 0 && gy < HH && gx0 >= 0 && gx0 <= WW - 8;
            uint4 pk = make_uint4(0u,0u,0u,0u);
            if (ok) {
                uint4 u1 = *(const uint4*)&buf[task * 8];
                float f1[8]; bf8(u1, f1);
                float v[8];
                if constexpr (MODE == 1) {
#pragma unroll
                    for (int k = 0; k < 8; k++)
                        v[k] = shrinkf(__builtin_fmaf(f1[k], s1, h1), lam);
                } else {
                    float f2[8]; bf8(rt2, f2);
#pragma unroll
                    for (int k = 0; k < 8; k++) {
                        float x = __builtin_fmaf(f2[k], s2v, h2)
                                + __builtin_fmaf(f1[k], s1, h1);
                        v[k] = shrinkf(x, lam);
                    }
                }
                pk.x = cvtpk(v[0], v[1]); pk.y = cvtpk(v[2], v[3]);
                pk.z = cvtpk(v[4], v[5]); pk.w = cvtpk(v[6], v[7]);
            }
            *(uint4*)&buf[task * 8] = pk;   // OOB -> literal zero
        };
        X(0, r2.a); X(1, r2.b); X(2, r2.c); X(3, r2.d); X(4, r2.e);
        X(5, r2.f); X(6, r2.g); X(7, r2.h); X(8, r2.i); X(9, r2.j);
    };

    // MFMA + epilogue + per-wave partials for one tile
    auto mfma_store = [&](const unsigned short* buf, int by, int bx, int gt) {
        const int r0w = wv * 32;
        f32x4 acc[2][8];
#pragma unroll
        for (int st = 0; st < 2; st++)
#pragma unroll
            for (int ct = 0; ct < 8; ct++)
                acc[st][ct] = (f32x4){0.f, 0.f, 0.f, 0.f};
#pragma unroll
        for (int ky = 0; ky < 5; ky++) {
            const short8 b = bfr[ky];
#pragma unroll
            for (int st = 0; st < 2; st++) {
                const unsigned short* ab = &buf[(r0w + st * 16 + lm + ky) * TPL + kb * 8];
#pragma unroll
                for (int ct = 0; ct < 8; ct++) {
                    short8 a = *(const short8*)(ab + ct * 16);
                    acc[st][ct] = __builtin_amdgcn_mfma_f32_16x16x32_bf16(a, b, acc[st][ct], 0, 0, 0);
                }
            }
        }
        float s = 0.f, q = 0.f;
#pragma unroll
        for (int st = 0; st < 2; st++) {
#pragma unroll
            for (int ct = 0; ct < 8; ct++) {
                const f32x4 a = acc[st][ct];
                const int grow0 = by + r0w + st * 16 + kb * 4;
                const size_t base = ibase + (size_t)grow0 * WW + bx + ct * 16 + lm;
                if constexpr (OBF) {
                    unsigned p01 = cvtpk(a[0] + b0, a[1] + b0);
                    unsigned p23 = cvtpk(a[2] + b0, a[3] + b0);
                    outbf[base]          = (unsigned short)(p01 & 0xffffu);
                    outbf[base + WW]     = (unsigned short)(p01 >> 16);
                    outbf[base + 2 * WW] = (unsigned short)(p23 & 0xffffu);
                    outbf[base + 3 * WW] = (unsigned short)(p23 >> 16);
                    float fr0 = lo2f(p01), fr1 = hi2f(p01), fr2 = lo2f(p23), fr3 = hi2f(p23);
                    s += fr0 + fr1 + fr2 + fr3;
                    q = __builtin_fmaf(fr0, fr0, __builtin_fmaf(fr1, fr1,
                        __builtin_fmaf(fr2, fr2, __builtin_fmaf(fr3, fr3, q))));
                } else {
                    float f0 = a[0] + b0, f1v = a[1] + b0, f2v = a[2] + b0, f3v = a[3] + b0;
                    outf32[base]          = f0;
                    outf32[base + WW]     = f1v;
                    outf32[base + 2 * WW] = f2v;
                    outf32[base + 3 * WW] = f3v;
                    s += f0 + f1v + f2v + f3v;
                    q = __builtin_fmaf(f0, f0, __builtin_fmaf(f1v, f1v,
                        __builtin_fmaf(f2v, f2v, __builtin_fmaf(f3v, f3v, q))));
                }
            }
        }
#pragma unroll
        for (int off = 32; off > 0; off >>= 1) {
            s += __shfl_xor(s, off);
            q += __shfl_xor(q, off);
        }
        if (lane == 0) {
            partials[(gt * 4 + wv) * 2]     = s;
            partials[(gt * 4 + wv) * 2 + 1] = q;
        }
    };

    // ---------------- pipeline ----------------
    issue_t1(by0, bx0, bufA);              // tile0 t1 -> bufA (async)
    R10 rT0{}, rT1{};
    if constexpr (MODE == 2) load_t2(by0, bx0, rT0);

    // stats (its barrier drains all staging above)
    if constexpr (MODE == 1) {
        stats_fast(prevPart, sbuf, tid, lane, wv, gamma[0], beta[0], s1, h1);
        lam = lambd[0];
        if (lin == 0 && tid == 0) { statsOut[0] = s1; statsOut[1] = h1; }
    } else {
        stats_fast(prevPart, sbuf, tid, lane, wv, gamma[0], beta[0], s2v, h2);
        s1 = statsIn[0]; h1 = statsIn[1];
        lam = lambd[1];
    }

    xform(by0, bx0, bufA, rT0);            // tile0 transform in place
    __syncthreads();                       // bufA visible to all waves

    issue_t1(by1, bx1, bufB);              // tile1 t1 -> bufB (async, overlaps below)
    if constexpr (MODE == 2) load_t2(by1, bx1, rT1);

    mfma_store(bufA, by0, bx0, g0);        // MFMA0 + store0 (overlaps tile1 reads)
    __syncthreads();                       // drains vmcnt -> bufB raw complete

    xform(by1, bx1, bufB, rT1);            // tile1 transform in place
    __syncthreads();

    mfma_store(bufB, by1, bx1, g1);        // MFMA1 + store1
}

// out = shrink(n3(t3) + n1(t1), lambd[2]); reduces P3 in-kernel (round-15)
template <bool T3BF>
__global__ __launch_bounds__(256) void final_k(
    const unsigned short* __restrict__ t1,
    const unsigned short* __restrict__ t3b,
    float* __restrict__ io,
    const float* __restrict__ p3,
    const float* __restrict__ statsIn,
    const float* __restrict__ gamma,
    const float* __restrict__ beta,
    const float* __restrict__ lambd)
{
    __shared__ double sbuf[8];
    const int tid = threadIdx.x;
    const int lane = tid & 63;
    const int wv = tid >> 6;

    float s3, h3;
    stats_fast(p3, sbuf, tid, lane, wv, gamma[0], beta[0], s3, h3);
    const float s1 = statsIn[0], h1 = statsIn[1];
    const float lam = lambd[2];

#pragma unroll
    for (int c = 0; c < 8; c++) {
        const size_t idx = ((size_t)c * 1024 + blockIdx.x) * 256 + tid;
        const size_t base = idx * 8;

        uint4 u1 = *(const uint4*)(t1 + base);
        float f1[8]; bf8(u1, f1);

        float t3v[8];
        if constexpr (T3BF) {
            uint4 u3 = *(const uint4*)(t3b + base);
            bf8(u3, t3v);
        } else {
            float4 a0 = *(const float4*)(io + base);
            float4 a1 = *(const float4*)(io + base + 4);
            t3v[0]=a0.x; t3v[1]=a0.y; t3v[2]=a0.z; t3v[3]=a0.w;
            t3v[4]=a1.x; t3v[5]=a1.y; t3v[6]=a1.z; t3v[7]=a1.w;
        }

        float r[8];
#pragma unroll
        for (int k = 0; k < 8; k++) {
            float v = __builtin_fmaf(t3v[k], s3, h3) + __builtin_fmaf(f1[k], s1, h1);
            r[k] = shrinkf(v, lam);
        }
        *(float4*)(io + base)     = make_float4(r[0], r[1], r[2], r[3]);
        *(float4*)(io + base + 4) = make_float4(r[4], r[5], r[6], r[7]);
    }
}

extern "C" void kernel_launch(void* const* d_in, const int* in_sizes, int n_in,
                              void* d_out, int out_size, void* d_ws, size_t ws_size,
                              hipStream_t stream)
{
    const float* y     = (const float*)d_in[0];
    const float* wgt   = (const float*)d_in[1];
    const float* bias  = (const float*)d_in[2];
    const float* gamma = (const float*)d_in[3];
    const float* beta  = (const float*)d_in[4];
    const float* lambd = (const float*)d_in[5];
    float* out = (float*)d_out;

    char* ws = (char*)d_ws;
    unsigned short* t1 = (unsigned short*)ws;                    // 33,554,432 B
    unsigned short* t2 = (unsigned short*)(ws + 33554432ull);    // 33,554,432 B
    unsigned short* t3 = (unsigned short*)(ws + 67108864ull);    // 33,554,432 B
    const bool t3bf = (ws_size >= 100761608ull);
    const size_t poff = t3bf ? 100663296ull : 67108864ull;
    float* p1    = (float*)(ws + poff);                 // 32 KB (4096 pairs)
    float* p2    = (float*)(ws + poff + 32768ull);      // 32 KB
    float* p3    = (float*)(ws + poff + 65536ull);      // 32 KB
    float* stats = (float*)(ws + poff + 98304ull);      // 8 B

    dim3 blk(256, 1, 1);
    conv_k<0, true><<<dim3(1024,1,1), blk, 0, stream>>>(
        y, nullptr, nullptr, t1, nullptr, wgt, bias, lambd, p1);
    conv2t_k<1, true><<<dim3(512,1,1), blk, 0, stream>>>(
        t1, nullptr, t2, nullptr, wgt, bias, p1, nullptr, stats,
        gamma, beta, lambd, p2);
    if (t3bf) {
        conv2t_k<2, true><<<dim3(512,1,1), blk, 0, stream>>>(
            t1, t2, t3, nullptr, wgt, bias, p2, stats, nullptr,
            gamma, beta, lambd, p3);
        final_k<true><<<dim3(1024,1,1), blk, 0, stream>>>(
            t1, t3, out, p3, stats, gamma, beta, lambd);
    } else {
        conv2t_k<2, false><<<dim3(512,1,1), blk, 0, stream>>>(
            t1, t2, nullptr, out, wgt, bias, p2, stats, nullptr,
            gamma, beta, lambd, p3);
        final_k<false><<<dim3(1024,1,1), blk, 0, stream>>>(
            t1, nullptr, out, p3, stats, gamma, beta, lambd);
    }
}

// Round 17
// 91.265 us; speedup vs baseline: 1.1464x; 1.1464x over previous
//
#include <hip/hip_runtime.h>
#include <math.h>

#define HH 512
#define WW 512
#define NTOT (64u*512u*512u)
#define TS 128
#define TROWS 132
#define TCH 18
#define TPIT 152        // LDS pitch (bf16): 304 B/row, 16B-aligned
#define NTASK (TROWS*TCH)   // 2376
#define NITER 10
#define NPART 4096          // per-wave partial pairs (1024 blocks x 4 waves)

typedef __attribute__((ext_vector_type(8))) short short8;
typedef __attribute__((ext_vector_type(4))) float f32x4;

__device__ __forceinline__ float fsqrtf(float x) { return __builtin_amdgcn_sqrtf(x); }

__device__ __forceinline__ float shrinkf(float x, float l) {
    float a = x - l, b = x + l;
    return x + 0.5f * (fsqrtf(__builtin_fmaf(a, a, 1.f)) - fsqrtf(__builtin_fmaf(b, b, 1.f)));
}

__device__ __forceinline__ float bf2f(unsigned int u) {
    union { unsigned int i; float f; } cv; cv.i = u << 16; return cv.f;
}
__device__ __forceinline__ float lo2f(unsigned int p) {
    union { unsigned int i; float f; } cv; cv.i = p << 16; return cv.f;
}
__device__ __forceinline__ float hi2f(unsigned int p) {
    union { unsigned int i; float f; } cv; cv.i = p & 0xffff0000u; return cv.f;
}

// v_cvt_pk_bf16_f32 (RNE): dst = bf16(lo) | (bf16(hi) << 16)
__device__ __forceinline__ unsigned int cvtpk(float lo, float hi) {
    unsigned int r;
    asm("v_cvt_pk_bf16_f32 %0, %1, %2" : "=v"(r) : "v"(lo), "v"(hi));
    return r;
}

__device__ __forceinline__ void bf8(uint4 u, float* f) {
    f[0] = bf2f(u.x & 0xffffu); f[1] = bf2f(u.x >> 16);
    f[2] = bf2f(u.y & 0xffffu); f[3] = bf2f(u.y >> 16);
    f[4] = bf2f(u.z & 0xffffu); f[5] = bf2f(u.z >> 16);
    f[6] = bf2f(u.w & 0xffffu); f[7] = bf2f(u.w >> 16);
}

// Fast stats reduce over NPART per-wave partial pairs: 16 pairs/thread (f64)
// -> wave butterfly -> 4 LDS slots -> ONE barrier -> combine. Deterministic.
__device__ __forceinline__ void stats_fast(
    const float* __restrict__ part, double* __restrict__ sbuf,
    int tid, int lane, int wv,
    float gam, float bet, float& scl_out, float& shf_out)
{
    double sd = 0.0, qd = 0.0;
#pragma unroll
    for (int k = 0; k < 16; k++) {
        const int i = tid + k * 256;
        sd += (double)part[2 * i];
        qd += (double)part[2 * i + 1];
    }
#pragma unroll
    for (int off = 32; off > 0; off >>= 1) {
        sd += __shfl_xor(sd, off);
        qd += __shfl_xor(qd, off);
    }
    if (lane == 0) { sbuf[2 * wv] = sd; sbuf[2 * wv + 1] = qd; }
    __syncthreads();
    const double S = sbuf[0] + sbuf[2] + sbuf[4] + sbuf[6];
    const double Q = sbuf[1] + sbuf[3] + sbuf[5] + sbuf[7];
    const double mean = S / (double)NTOT;
    const double var  = Q / (double)NTOT - mean * mean;
    const double scl  = (double)gam / sqrt(var + 1e-5);
    scl_out = (float)scl;
    shf_out = (float)((double)bet - mean * scl);
}

// MFMA conv (Toeplitz): out[ct] += sum_ky A_ky(16x32) x B_ky(32x16)
//   A_ky[m][k] = tile[row0+m+ky][ct*16 + k]  (tile col t <-> gx = bx + t - 8)
//   B_ky[k][n] = w[ky][k-n-6] if 0 <= k-n-6 <= 4 else 0
// MODE 0: y (fp32) identity -> t1 bf16
// MODE 1: stats(P1) -> (s1,h1); t1 -> shrink(n1,l0) -> t2; statsOut=(s1,h1)
// MODE 2: stats(P2) -> (s2,h2); reads (s1,h1); t1,t2 -> shrink -> t3/out
// Grid: 1024 x 1-D; bijective XCD swizzle (1024 % 8 == 0).
template <int MODE, bool OBF>
__global__ __launch_bounds__(256, 4) void conv_k(
    const float* __restrict__ yin,
    const unsigned short* __restrict__ t1,
    const unsigned short* __restrict__ t2,
    unsigned short* __restrict__ outbf,
    float* __restrict__ outf32,
    const float* __restrict__ wgt,
    const float* __restrict__ bias,
    const float* __restrict__ prevPart,
    const float* __restrict__ statsIn,
    float* __restrict__ statsOut,
    const float* __restrict__ gamma,
    const float* __restrict__ beta,
    const float* __restrict__ lambd,
    float* __restrict__ partials)
{
    __shared__ unsigned short tile[TROWS * TPIT];   // 40,128 B
    __shared__ double sbuf[8];                      // stats scratch

    const int tid = threadIdx.x;
    const int lin = blockIdx.x;
    // XCD-bijective swizzle: XCD k owns tiles [k*128, (k+1)*128) = 8 images
    const int swz = ((lin & 7) << 7) | (lin >> 3);
    const int img = swz >> 4;
    const int rem = swz & 15;
    const int by = ((rem >> 2) & 3) * TS;
    const int bx = (rem & 3) * TS;
    const size_t ibase = (size_t)img * (HH * WW);

    const int lane = tid & 63;
    const int lm = lane & 15;
    const int kb = lane >> 4;
    const int wv = tid >> 6;

    // uniform weights -> SGPRs; lane-local B fragments
    float wloc[25];
#pragma unroll
    for (int i = 0; i < 25; i++) wloc[i] = wgt[i];
    const int basei = kb * 8 - lm - 6;
    short8 bfr[5];
#pragma unroll
    for (int ky = 0; ky < 5; ky++) {
        unsigned pkw[4];
#pragma unroll
        for (int jj = 0; jj < 4; jj++) {
            float v0 = 0.f, v1 = 0.f;
            const int i0 = basei + 2 * jj, i1 = i0 + 1;
#pragma unroll
            for (int t = 0; t < 5; t++) {
                if (i0 == t) v0 = wloc[ky * 5 + t];
                if (i1 == t) v1 = wloc[ky * 5 + t];
            }
            pkw[jj] = cvtpk(v0, v1);
        }
        union { unsigned u[4]; short8 s; } cv;
        cv.u[0]=pkw[0]; cv.u[1]=pkw[1]; cv.u[2]=pkw[2]; cv.u[3]=pkw[3];
        bfr[ky] = cv.s;
    }

    auto loadT = [&](int task, uint4& A, uint4& B) {
        A = make_uint4(0u,0u,0u,0u); B = make_uint4(0u,0u,0u,0u);
        const int row = task / TCH;
        const int ch  = task - row * TCH;
        const int gy  = by + row - 2;
        const int gx0 = bx + ch * 8 - 8;
        if (task < NTASK && gy >= 0 && gy < HH && gx0 >= 0 && gx0 <= WW - 8) {
            const size_t g = ibase + (size_t)gy * WW + gx0;
            if constexpr (MODE == 0) {
                A = *(const uint4*)(yin + g);
                B = *(const uint4*)(yin + g + 4);
            } else if constexpr (MODE == 1) {
                A = *(const uint4*)(t1 + g);
            } else {
                A = *(const uint4*)(t1 + g);
                B = *(const uint4*)(t2 + g);
            }
        }
    };

    // issue first 3 tasks' loads BEFORE stats (latency overlap)
    uint4 sA0, sB0, sA1, sB1, sA2, sB2;
    loadT(tid,        sA0, sB0);
    loadT(tid + 256,  sA1, sB1);
    loadT(tid + 512,  sA2, sB2);

    float s1 = 0.f, h1 = 0.f, s2v = 0.f, h2 = 0.f, lam = 0.f;
    if constexpr (MODE == 1) {
        stats_fast(prevPart, sbuf, tid, lane, wv, gamma[0], beta[0], s1, h1);
        lam = lambd[0];
        if (lin == 0 && tid == 0) { statsOut[0] = s1; statsOut[1] = h1; }
    }
    if constexpr (MODE == 2) {
        stats_fast(prevPart, sbuf, tid, lane, wv, gamma[0], beta[0], s2v, h2);
        s1 = statsIn[0]; h1 = statsIn[1];
        lam = lambd[1];
    }

    auto procT = [&](int task, uint4 A, uint4 B) {
        const int row = task / TCH;
        const int ch  = task - row * TCH;
        uint4 pk = make_uint4(0u,0u,0u,0u);
        if constexpr (MODE == 0) {
            const float4 a = *(const float4*)&A;
            const float4 b = *(const float4*)&B;
            pk.x = cvtpk(a.x, a.y); pk.y = cvtpk(a.z, a.w);
            pk.z = cvtpk(b.x, b.y); pk.w = cvtpk(b.z, b.w);
        } else if constexpr (MODE == 1) {
            float f1[8]; bf8(A, f1);
            float v[8];
#pragma unroll
            for (int k = 0; k < 8; k++)
                v[k] = shrinkf(__builtin_fmaf(f1[k], s1, h1), lam);
            pk.x = cvtpk(v[0], v[1]); pk.y = cvtpk(v[2], v[3]);
            pk.z = cvtpk(v[4], v[5]); pk.w = cvtpk(v[6], v[7]);
        } else {
            float f1[8], f2[8]; bf8(A, f1); bf8(B, f2);
            float v[8];
#pragma unroll
            for (int k = 0; k < 8; k++) {
                float x = __builtin_fmaf(f2[k], s2v, h2)
                        + __builtin_fmaf(f1[k], s1, h1);
                v[k] = shrinkf(x, lam);
            }
            pk.x = cvtpk(v[0], v[1]); pk.y = cvtpk(v[2], v[3]);
            pk.z = cvtpk(v[4], v[5]); pk.w = cvtpk(v[6], v[7]);
        }
        // OOB chunk: reference zero-pads the post-transform conv input
        const int gy  = by + row - 2;
        const int gx0 = bx + ch * 8 - 8;
        if (!(gy >= 0 && gy < HH && gx0 >= 0 && gx0 <= WW - 8))
            pk = make_uint4(0u,0u,0u,0u);
        *(uint4*)&tile[row * TPIT + ch * 8] = pk;
    };

#pragma unroll
    for (int t = 0; t < NITER; t++) {
        const int task = tid + t * 256;
        if (task < NTASK) procT(task, sA0, sB0);
        sA0 = sA1; sB0 = sB1;
        sA1 = sA2; sB1 = sB2;
        if (t + 3 < NITER) loadT(tid + (t + 3) * 256, sA2, sB2);
        else { sA2 = make_uint4(0u,0u,0u,0u); sB2 = make_uint4(0u,0u,0u,0u); }
    }

    const float b0 = bias[0];
    __syncthreads();

    // ---- MFMA phase: wave wv owns 32 output rows x 128 cols ----
    const int r0w = wv * 32;

    f32x4 acc[2][8];
#pragma unroll
    for (int st = 0; st < 2; st++)
#pragma unroll
        for (int ct = 0; ct < 8; ct++)
            acc[st][ct] = (f32x4){0.f, 0.f, 0.f, 0.f};

#pragma unroll
    for (int ky = 0; ky < 5; ky++) {
        const short8 b = bfr[ky];
#pragma unroll
        for (int st = 0; st < 2; st++) {
            const unsigned short* ab = &tile[(r0w + st * 16 + lm + ky) * TPIT + kb * 8];
#pragma unroll
            for (int ct = 0; ct < 8; ct++) {
                short8 a = *(const short8*)(ab + ct * 16);
                acc[st][ct] = __builtin_amdgcn_mfma_f32_16x16x32_bf16(a, b, acc[st][ct], 0, 0, 0);
            }
        }
    }

    // ---- epilogue: lane holds rows kb*4+e, col lm of each 16x16 tile ----
    float s = 0.f, q = 0.f;
#pragma unroll
    for (int st = 0; st < 2; st++) {
#pragma unroll
        for (int ct = 0; ct < 8; ct++) {
            const f32x4 a = acc[st][ct];
            const int grow0 = by + r0w + st * 16 + kb * 4;
            const size_t base = ibase + (size_t)grow0 * WW + bx + ct * 16 + lm;
            if constexpr (OBF) {
                unsigned p01 = cvtpk(a[0] + b0, a[1] + b0);
                unsigned p23 = cvtpk(a[2] + b0, a[3] + b0);
                outbf[base]          = (unsigned short)(p01 & 0xffffu);
                outbf[base + WW]     = (unsigned short)(p01 >> 16);
                outbf[base + 2 * WW] = (unsigned short)(p23 & 0xffffu);
                outbf[base + 3 * WW] = (unsigned short)(p23 >> 16);
                float fr0 = lo2f(p01), fr1 = hi2f(p01), fr2 = lo2f(p23), fr3 = hi2f(p23);
                s += fr0 + fr1 + fr2 + fr3;
                q = __builtin_fmaf(fr0, fr0, __builtin_fmaf(fr1, fr1,
                    __builtin_fmaf(fr2, fr2, __builtin_fmaf(fr3, fr3, q))));
            } else {
                float f0 = a[0] + b0, f1v = a[1] + b0, f2v = a[2] + b0, f3v = a[3] + b0;
                outf32[base]          = f0;
                outf32[base + WW]     = f1v;
                outf32[base + 2 * WW] = f2v;
                outf32[base + 3 * WW] = f3v;
                s += f0 + f1v + f2v + f3v;
                q = __builtin_fmaf(f0, f0, __builtin_fmaf(f1v, f1v,
                    __builtin_fmaf(f2v, f2v, __builtin_fmaf(f3v, f3v, q))));
            }
        }
    }

    // ---- tail: per-wave butterfly, NO barriers; one partial pair per wave ----
#pragma unroll
    for (int off = 32; off > 0; off >>= 1) {
        s += __shfl_xor(s, off);
        q += __shfl_xor(q, off);
    }
    if (lane == 0) {
        partials[(swz * 4 + wv) * 2]     = s;
        partials[(swz * 4 + wv) * 2 + 1] = q;
    }
}

// out = shrink(n3(t3) + n1(t1), lambd[2]); reduces P3 -> (s3,h3) in-kernel.
template <bool T3BF>
__global__ __launch_bounds__(256) void final_k(
    const unsigned short* __restrict__ t1,
    const unsigned short* __restrict__ t3b,
    float* __restrict__ io,
    const float* __restrict__ p3,
    const float* __restrict__ statsIn,
    const float* __restrict__ gamma,
    const float* __restrict__ beta,
    const float* __restrict__ lambd)
{
    __shared__ double sbuf[8];
    const int tid = threadIdx.x;
    const int lane = tid & 63;
    const int wv = tid >> 6;

    float s3, h3;
    stats_fast(p3, sbuf, tid, lane, wv, gamma[0], beta[0], s3, h3);
    const float s1 = statsIn[0], h1 = statsIn[1];
    const float lam = lambd[2];

#pragma unroll
    for (int c = 0; c < 8; c++) {
        const size_t idx = ((size_t)c * 1024 + blockIdx.x) * 256 + tid;
        const size_t base = idx * 8;

        uint4 u1 = *(const uint4*)(t1 + base);
        float f1[8]; bf8(u1, f1);

        float t3v[8];
        if constexpr (T3BF) {
            uint4 u3 = *(const uint4*)(t3b + base);
            bf8(u3, t3v);
        } else {
            float4 a0 = *(const float4*)(io + base);
            float4 a1 = *(const float4*)(io + base + 4);
            t3v[0]=a0.x; t3v[1]=a0.y; t3v[2]=a0.z; t3v[3]=a0.w;
            t3v[4]=a1.x; t3v[5]=a1.y; t3v[6]=a1.z; t3v[7]=a1.w;
        }

        float r[8];
#pragma unroll
        for (int k = 0; k < 8; k++) {
            float v = __builtin_fmaf(t3v[k], s3, h3) + __builtin_fmaf(f1[k], s1, h1);
            r[k] = shrinkf(v, lam);
        }
        *(float4*)(io + base)     = make_float4(r[0], r[1], r[2], r[3]);
        *(float4*)(io + base + 4) = make_float4(r[4], r[5], r[6], r[7]);
    }
}

extern "C" void kernel_launch(void* const* d_in, const int* in_sizes, int n_in,
                              void* d_out, int out_size, void* d_ws, size_t ws_size,
                              hipStream_t stream)
{
    const float* y     = (const float*)d_in[0];
    const float* wgt   = (const float*)d_in[1];
    const float* bias  = (const float*)d_in[2];
    const float* gamma = (const float*)d_in[3];
    const float* beta  = (const float*)d_in[4];
    const float* lambd = (const float*)d_in[5];
    float* out = (float*)d_out;

    char* ws = (char*)d_ws;
    unsigned short* t1 = (unsigned short*)ws;                    // 33,554,432 B
    unsigned short* t2 = (unsigned short*)(ws + 33554432ull);    // 33,554,432 B
    unsigned short* t3 = (unsigned short*)(ws + 67108864ull);    // 33,554,432 B
    const bool t3bf = (ws_size >= 100761608ull);
    const size_t poff = t3bf ? 100663296ull : 67108864ull;
    float* p1    = (float*)(ws + poff);                 // 32 KB (4096 pairs)
    float* p2    = (float*)(ws + poff + 32768ull);      // 32 KB
    float* p3    = (float*)(ws + poff + 65536ull);      // 32 KB
    float* stats = (float*)(ws + poff + 98304ull);      // 8 B

    dim3 grid(1024, 1, 1), blk(256, 1, 1);
    conv_k<0, true><<<grid, blk, 0, stream>>>(y, nullptr, nullptr, t1, nullptr,
                                              wgt, bias, nullptr, nullptr, nullptr,
                                              gamma, beta, lambd, p1);
    conv_k<1, true><<<grid, blk, 0, stream>>>(nullptr, t1, nullptr, t2, nullptr,
                                              wgt, bias, p1, nullptr, stats,
                                              gamma, beta, lambd, p2);
    if (t3bf) {
        conv_k<2, true><<<grid, blk, 0, stream>>>(nullptr, t1, t2, t3, nullptr,
                                                  wgt, bias, p2, stats, nullptr,
                                                  gamma, beta, lambd, p3);
        final_k<true><<<grid, blk, 0, stream>>>(t1, t3, out, p3, stats,
                                                gamma, beta, lambd);
    } else {
        conv_k<2, false><<<grid, blk, 0, stream>>>(nullptr, t1, t2, nullptr, out,
                                                   wgt, bias, p2, stats, nullptr,
                                                   gamma, beta, lambd, p3);
        final_k<false><<<grid, blk, 0, stream>>>(t1, nullptr, out, p3, stats,
                                                 gamma, beta, lambd);
    }
}